// Round 2
// baseline (369.991 us; speedup 1.0000x reference)
//
#include <hip/hip_runtime.h>

#define B_   2
#define H_   16
#define HK_  4
#define G_   4
#define S_   2048
#define D_   128
#define I_   2048

#define BM   128
#define BN   64
#define TPB  256          // 4 waves
#define NIT  (I_/BN)      // 32

#define LDK  136          // Ks/Us row stride (f16): 128+8 -> 272B rows, 16B aligned, conflict-free b128

static constexpr float SCALE = 0.08838834764831845f;  // 1/sqrt(128)

typedef _Float16 h8v __attribute__((ext_vector_type(8)));
typedef _Float16 h4v __attribute__((ext_vector_type(4)));
typedef float    f4v __attribute__((ext_vector_type(4)));

#define KU_ELEMS (HK_ * I_ * D_)   // 1048576 per tensor

// ---------------- prologue: K,U -> f16 row-major ----------------
__global__ __launch_bounds__(256) void cvt_ku(const float* __restrict__ Kg,
                                              const float* __restrict__ Ug,
                                              _Float16* __restrict__ Kh,
                                              _Float16* __restrict__ Uh) {
    const int bid = blockIdx.x;
    const size_t off = ((size_t)(bid & 511) * 256 + threadIdx.x) * 8;
    const float* src = (bid < 512) ? (Kg + off) : (Ug + off);
    _Float16*    dst = (bid < 512) ? (Kh + off) : (Uh + off);
    const float4 a = *(const float4*)src;
    const float4 c = *(const float4*)(src + 4);
    h8v v;
    v[0] = (_Float16)a.x; v[1] = (_Float16)a.y; v[2] = (_Float16)a.z; v[3] = (_Float16)a.w;
    v[4] = (_Float16)c.x; v[5] = (_Float16)c.y; v[6] = (_Float16)c.z; v[7] = (_Float16)c.w;
    *(h8v*)dst = v;
}

// ---------------- prologue: V -> f16 transposed Vt[kh][d][i] ----------------
__global__ __launch_bounds__(256) void cvt_vt(const float* __restrict__ Vg,
                                              _Float16* __restrict__ Vt) {
    __shared__ _Float16 T[D_ * 72];   // [d][i-within-tile], pad 64->72
    const int kh    = blockIdx.x >> 5;   // grid = 4 heads * 32 i-tiles
    const int itile = blockIdx.x & 31;
    const int i0    = itile * 64;
    const int tid   = threadIdx.x;
    {   // read 64 i-rows x 128 d, coalesced along d; scatter into T
        const int i = tid >> 2, dbase = (tid & 3) * 32;
        const float* vp = Vg + ((size_t)kh * I_ + (i0 + i)) * D_ + dbase;
#pragma unroll
        for (int j = 0; j < 32; j += 4) {
            const float4 x = *(const float4*)(vp + j);
            T[(dbase + j + 0) * 72 + i] = (_Float16)x.x;
            T[(dbase + j + 1) * 72 + i] = (_Float16)x.y;
            T[(dbase + j + 2) * 72 + i] = (_Float16)x.z;
            T[(dbase + j + 3) * 72 + i] = (_Float16)x.w;
        }
    }
    __syncthreads();
    {   // write d-rows, coalesced along i
        const int d = tid >> 1, ic = (tid & 1) * 32;
        _Float16* op = Vt + ((size_t)kh * D_ + d) * I_ + i0 + ic;
#pragma unroll
        for (int j = 0; j < 32; j += 8)
            *(h8v*)(op + j) = *(const h8v*)(&T[d * 72 + ic + j]);
    }
}

// ---------------- main fused kernel ----------------
__global__ __launch_bounds__(TPB, 2) void flashmlp_kernel(
    const float* __restrict__ Qg,
    const _Float16* __restrict__ Kh,
    const _Float16* __restrict__ Uh,
    const _Float16* __restrict__ Vth,
    float* __restrict__ Og)
{
    // LDS: 2 * 64*136 f16 = 69632 B -> 2 blocks/CU
    __shared__ _Float16 Ks[BN * LDK];
    __shared__ _Float16 Us[BN * LDK];

    // XCD swizzle: xcd = bid&7 -> kv-head = xcd>>1 (head's 1.5MB f16 K/U/V per XCD L2)
    const int bid   = blockIdx.x;
    const int xcd   = bid & 7;
    const int kh    = xcd >> 1;
    const int j     = ((bid >> 3) << 1) | (xcd & 1);
    const int stile = j & 15;
    const int bg    = j >> 4;
    const int b     = bg >> 2;
    const int g     = bg & 3;
    const int h     = kh * G_ + g;

    const int tid  = threadIdx.x;
    const int wave = tid >> 6;
    const int lane = tid & 63;
    const int m16  = lane & 15;
    const int qq   = lane >> 4;

    const size_t qbase = ((size_t)(b * H_ + h) * S_ + (size_t)stile * BM) * D_;
    const size_t kub   = (size_t)kh * I_ * D_;   // f16 elems
    const size_t vtb   = (size_t)kh * D_ * I_;   // Vt[d][i]

    // ---- Q fragments (used as B-operand of M^T), pre-scaled by 1/sqrt(D)
    h8v qf[2][4];
#pragma unroll
    for (int rt = 0; rt < 2; ++rt) {
        const float* qp = Qg + qbase + (size_t)(wave * 32 + rt * 16 + m16) * D_;
#pragma unroll
        for (int ks = 0; ks < 4; ++ks) {
            const float4 a = *(const float4*)(qp + ks * 32 + qq * 8);
            const float4 c = *(const float4*)(qp + ks * 32 + qq * 8 + 4);
            h8v v;
            v[0] = (_Float16)(a.x * SCALE); v[1] = (_Float16)(a.y * SCALE);
            v[2] = (_Float16)(a.z * SCALE); v[3] = (_Float16)(a.w * SCALE);
            v[4] = (_Float16)(c.x * SCALE); v[5] = (_Float16)(c.y * SCALE);
            v[6] = (_Float16)(c.z * SCALE); v[7] = (_Float16)(c.w * SCALE);
            qf[rt][ks] = v;
        }
    }

    f4v acc[2][8];
#pragma unroll
    for (int rt = 0; rt < 2; ++rt)
#pragma unroll
        for (int dt = 0; dt < 8; ++dt)
            acc[rt][dt] = f4v{0.f, 0.f, 0.f, 0.f};

    const int srow = tid >> 2;          // 0..63
    const int scol = (tid & 3) * 32;    // 64B chunk base (f16 elems)

    // register prefetch of tile 0
    h8v kpre[4], upre[4];
    {
        const _Float16* kp = Kh + kub + (size_t)srow * D_ + scol;
        const _Float16* up = Uh + kub + (size_t)srow * D_ + scol;
#pragma unroll
        for (int c = 0; c < 4; ++c) {
            kpre[c] = *(const h8v*)(kp + c * 8);
            upre[c] = *(const h8v*)(up + c * 8);
        }
    }

    for (int it = 0; it < NIT; ++it) {
        const int i0 = it * BN;

        __syncthreads();   // readers of previous tile done
#pragma unroll
        for (int c = 0; c < 4; ++c) {
            *(h8v*)(&Ks[srow * LDK + scol + c * 8]) = kpre[c];
            *(h8v*)(&Us[srow * LDK + scol + c * 8]) = upre[c];
        }
        __syncthreads();

        // issue next tile's global loads now; latency hides under compute
        {
            const int nx = (it + 1) & (NIT - 1);
            const _Float16* kp = Kh + kub + (size_t)(nx * BN + srow) * D_ + scol;
            const _Float16* up = Uh + kub + (size_t)(nx * BN + srow) * D_ + scol;
#pragma unroll
            for (int c = 0; c < 4; ++c) {
                kpre[c] = *(const h8v*)(kp + c * 8);
                upre[c] = *(const h8v*)(up + c * 8);
            }
        }

        // ---- M^T = K Q^T, N^T = U Q^T  (D[m=i][n=s]; swapped operands)
        f4v am[2][4], an[2][4];
#pragma unroll
        for (int rt = 0; rt < 2; ++rt)
#pragma unroll
            for (int ct = 0; ct < 4; ++ct) {
                am[rt][ct] = f4v{0.f, 0.f, 0.f, 0.f};
                an[rt][ct] = f4v{0.f, 0.f, 0.f, 0.f};
            }
#pragma unroll
        for (int ct = 0; ct < 4; ++ct) {
#pragma unroll
            for (int ks = 0; ks < 4; ++ks) {
                const h8v kf = *(const h8v*)(&Ks[(ct * 16 + m16) * LDK + ks * 32 + qq * 8]);
                const h8v uf = *(const h8v*)(&Us[(ct * 16 + m16) * LDK + ks * 32 + qq * 8]);
#pragma unroll
                for (int rt = 0; rt < 2; ++rt) {
                    am[rt][ct] = __builtin_amdgcn_mfma_f32_16x16x32_f16(kf, qf[rt][ks], am[rt][ct], 0, 0, 0);
                    an[rt][ct] = __builtin_amdgcn_mfma_f32_16x16x32_f16(uf, qf[rt][ks], an[rt][ct], 0, 0, 0);
                }
            }
        }

        // ---- gate in registers: A^T tile is directly the 16x16x16 A-operand
        h4v ag[2][4];
#pragma unroll
        for (int rt = 0; rt < 2; ++rt)
#pragma unroll
            for (int ct = 0; ct < 4; ++ct)
#pragma unroll
                for (int r = 0; r < 4; ++r) {
                    const float mv = am[rt][ct][r];
                    const float nv = an[rt][ct][r];
                    const float sg = __builtin_amdgcn_rcpf(1.f + __expf(-mv));
                    ag[rt][ct][r] = (_Float16)(mv * sg * nv);
                }

        // ---- O += A V via 16x16x16; V B-frags straight from global (L1-resident tile)
#pragma unroll
        for (int ct = 0; ct < 4; ++ct) {
#pragma unroll
            for (int dt = 0; dt < 8; ++dt) {
                const h4v vf = *(const h4v*)(Vth + vtb + (size_t)(dt * 16 + m16) * I_
                                             + i0 + ct * 16 + qq * 4);
#pragma unroll
                for (int rt = 0; rt < 2; ++rt)
                    acc[rt][dt] = __builtin_amdgcn_mfma_f32_16x16x16f16(ag[rt][ct], vf, acc[rt][dt], 0, 0, 0);
            }
        }
    }

    // ---- epilogue: D[m=s][n=d], row = qq*4+r, col = m16
#pragma unroll
    for (int rt = 0; rt < 2; ++rt) {
#pragma unroll
        for (int r = 0; r < 4; ++r) {
            const int row = stile * BM + wave * 32 + rt * 16 + qq * 4 + r;
            float* op = Og + ((size_t)(b * H_ + h) * S_ + row) * D_;
#pragma unroll
            for (int dt = 0; dt < 8; ++dt)
                op[dt * 16 + m16] = acc[rt][dt][r];
        }
    }
}

extern "C" void kernel_launch(void* const* d_in, const int* in_sizes, int n_in,
                              void* d_out, int out_size, void* d_ws, size_t ws_size,
                              hipStream_t stream) {
    const float* Q = (const float*)d_in[0];
    const float* K = (const float*)d_in[1];
    const float* U = (const float*)d_in[2];
    const float* V = (const float*)d_in[3];
    float* out = (float*)d_out;

    _Float16* Kh  = (_Float16*)d_ws;
    _Float16* Uh  = Kh + KU_ELEMS;
    _Float16* Vth = Uh + KU_ELEMS;   // 6 MB total in d_ws

    cvt_ku<<<dim3(1024), dim3(256), 0, stream>>>(K, U, Kh, Uh);
    cvt_vt<<<dim3(128),  dim3(256), 0, stream>>>(V, Vth);

    const int grid = (S_ / BM) * B_ * H_;   // 512 blocks
    flashmlp_kernel<<<dim3(grid), dim3(TPB), 0, stream>>>(Q, Kh, Uh, Vth, out);
}